// Round 7
// baseline (99.073 us; speedup 1.0000x reference)
//
#include <hip/hip_runtime.h>
#include <stdint.h>

#define NPTS 8192
#define BATCH 4
#define CHUNK 512   // refs per block (LDS tile), queries per block
#define NJX (NPTS / CHUNK)  // 16 jx slices

typedef __attribute__((ext_vector_type(8))) short bf16x8;   // 8 bf16 = 4 VGPRs
typedef __attribute__((ext_vector_type(16))) float f32x16;  // 32x32 MFMA acc

// Accum: 13 floats + ticket counter, zeroed by prep (reads happen in later nodes)
struct Accum {
  float l1sum;         // [0]
  float count[BATCH];  // [1..4]
  float minsum[8];     // [5..12]  [dir*4+b]
  unsigned int ticket; // [13]
  float pad[2];
};

__device__ __forceinline__ unsigned short f2bf(float x) {  // RNE fp32->bf16
  union { float f; unsigned u; } v; v.f = x;
  unsigned r = v.u + 0x7FFFu + ((v.u >> 16) & 1u);
  return (unsigned short)(r >> 16);
}
__device__ __forceinline__ float bf2f(unsigned short h) {
  union { float f; unsigned u; } v; v.u = ((unsigned)h) << 16;
  return v.f;
}

using as1_t = __attribute__((address_space(1))) const unsigned int;
using as3_t = __attribute__((address_space(3))) unsigned int;
__device__ __forceinline__ void lds_load16(const void* g, void* l) {
  __builtin_amdgcn_global_load_lds((as1_t*)g, (as3_t*)l, 16, 0, 0);
}

// Pack layout (fragment order): per 32-point tile T, 64 chunks of 16 B:
// chunk T*64 + lane = K-slots [8*(lane>>5)..] of point T*32+(lane&31): fragment
// loads are lane-consecutive 16 B -> conflict-free and global_load_lds-able.
// A (ref):   k0-3=[-2x_h,-2x_h,-2x_l,-2x_l] k4-7=y k8-11=z k12-14=3-split(norm+pen) k15=0
// B (query): k0-3=[x_h,x_l,x_h,x_l]         k4-7=y k8-11=z k12-14=[1,1,1]          k15=0
// => D[ref m][query n] = (norm_r + pen) - 2 q.r  (exact hi/lo product pairing).
// Query norm + relu are applied in reduce: both commute with min over refs.
__device__ __forceinline__ void writeA(uint4* P, int T, int n,
                                       float x, float y, float z, float nn) {
  float ax = -2.f * x, ay = -2.f * y, az = -2.f * z;
  unsigned xh = f2bf(ax), xl = f2bf(ax - bf2f(xh));
  unsigned yh = f2bf(ay), yl = f2bf(ay - bf2f(yh));
  unsigned zh = f2bf(az), zl = f2bf(az - bf2f(zh));
  unsigned nh = f2bf(nn);
  float rem = nn - bf2f((unsigned short)nh);
  unsigned nm = f2bf(rem);
  unsigned nl = f2bf(rem - bf2f((unsigned short)nm));
  uint4 h0, h1;
  h0.x = xh | (xh << 16); h0.y = xl | (xl << 16);
  h0.z = yh | (yh << 16); h0.w = yl | (yl << 16);
  h1.x = zh | (zh << 16); h1.y = zl | (zl << 16);
  h1.z = nh | (nm << 16); h1.w = nl;
  P[T * 64 + n] = h0;
  P[T * 64 + 32 + n] = h1;
}
__device__ __forceinline__ void writeB(uint4* P, int T, int n,
                                       float x, float y, float z) {
  unsigned xh = f2bf(x), xl = f2bf(x - bf2f((unsigned short)xh));
  unsigned yh = f2bf(y), yl = f2bf(y - bf2f((unsigned short)yh));
  unsigned zh = f2bf(z), zl = f2bf(z - bf2f((unsigned short)zh));
  const unsigned ONE = 0x3F80u;
  unsigned ux = xh | (xl << 16), uy = yh | (yl << 16), uz = zh | (zl << 16);
  uint4 h0, h1;
  h0.x = ux; h0.y = ux; h0.z = uy; h0.w = uy;
  h1.x = uz; h1.y = uz; h1.z = ONE | (ONE << 16); h1.w = ONE;
  P[T * 64 + n] = h0;
  P[T * 64 + 32 + n] = h1;
}

__global__ __launch_bounds__(256) void prep_kernel(
    const float* __restrict__ pred, const float* __restrict__ target,
    const int* __restrict__ mask, const float* __restrict__ points,
    uint4* __restrict__ Apred, uint4* __restrict__ Aclean,
    uint4* __restrict__ Bclean, uint4* __restrict__ Bpred,
    float* __restrict__ qnClean, float* __restrict__ qnPred,
    float* __restrict__ l1part, Accum* __restrict__ acc) {
  int tid = threadIdx.x;
  int g = blockIdx.x * 256 + tid;  // 128 blocks x 256 = BATCH*NPTS
  if (g < 16) ((unsigned int*)acc)[g] = 0u;  // zero accumulators + ticket
  float px = pred[3 * g], py = pred[3 * g + 1], pz = pred[3 * g + 2];
  float tx = target[3 * g], ty = target[3 * g + 1], tz = target[3 * g + 2];
  float ox = points[3 * g], oy = points[3 * g + 1], oz = points[3 * g + 2];
  int m = mask[g];
  float cx = ox + tx, cy = oy + ty, cz = oz + tz;  // clean
  float qx = ox + px, qy = oy + py, qz = oz + pz;  // predicted denoised
  float cn = cx * cx + cy * cy + cz * cz;
  float qn = qx * qx + qy * qy + qz * qz;
  float pen = m ? 0.f : 1e9f;
  qnClean[g] = cn;
  qnPred[g] = qn;
  int T = g >> 5, n = g & 31;
  writeA(Apred, T, n, qx, qy, qz, qn + pen);   // dir0 refs = pred-denoised
  writeA(Aclean, T, n, cx, cy, cz, cn + pen);  // dir1 refs = clean
  writeB(Bclean, T, n, cx, cy, cz);            // dir0 queries = clean
  writeB(Bpred, T, n, qx, qy, qz);             // dir1 queries = pred-denoised

  // per-block L1 partial (summed by the last reduce block)
  float fm = (float)m;
  float l1c = fm * (fabsf(px - tx) + fabsf(py - ty) + fabsf(pz - tz)) * (1.f / 3.f);
  for (int off = 32; off; off >>= 1) l1c += __shfl_down(l1c, off);
  __shared__ float pl[4];
  if ((tid & 63) == 0) pl[tid >> 6] = l1c;
  __syncthreads();
  if (tid == 0) l1part[blockIdx.x] = pl[0] + pl[1] + pl[2] + pl[3];
}

// Block = (jx, qy, dir*4+b): 512 refs x 512 queries (r5 shape: 2048 blocks,
// 8 blocks/CU for latency hiding). Raw row-mins -> PRIVATE partial slice;
// no atomics, no fences in the hot kernel.
__global__ __launch_bounds__(256) void chamfer_kernel(
    const uint4* __restrict__ Apred, const uint4* __restrict__ Aclean,
    const uint4* __restrict__ Bclean, const uint4* __restrict__ Bpred,
    float* __restrict__ partial) {
  __shared__ uint4 Asm[1024];  // 16 KB: 16 ref tiles
  int z = blockIdx.z, dir = z >> 2, b = z & 3;
  const uint4* __restrict__ Ag = dir ? Aclean : Apred;
  const uint4* __restrict__ Bg = dir ? Bpred : Bclean;
  int jx = blockIdx.x, jbase = jx * CHUNK;  // refs
  int qbase = blockIdx.y * CHUNK;           // queries
  int tid = threadIdx.x;

  // stage refs -> LDS (lane-consecutive 16 B chunks, wave-uniform base)
  const uint4* Agp = Ag + (size_t)(b * NPTS + jbase) * 2;
#pragma unroll
  for (int it = 0; it < 4; it++) lds_load16(Agp + it * 256 + tid, &Asm[it * 256 + tid]);

  // query fragments straight from global (once per wave; coalesced, L2-hot)
  int lane = tid & 63, w = tid >> 6, n = lane & 31;
  const bf16x8* Bb = (const bf16x8*)(Bg + (size_t)(b * NPTS + qbase) * 2);
  bf16x8 bfr[4];
  float acc[4];
#pragma unroll
  for (int q = 0; q < 4; q++) {
    bfr[q] = Bb[(w * 4 + q) * 64 + lane];  // wave owns 4 query tiles (128 queries)
    acc[q] = 1e30f;
  }
  __syncthreads();  // drains vmcnt: LDS staging + B loads complete

  const bf16x8* Al = (const bf16x8*)Asm;
  f32x16 zacc = {0.f, 0.f, 0.f, 0.f, 0.f, 0.f, 0.f, 0.f,
                 0.f, 0.f, 0.f, 0.f, 0.f, 0.f, 0.f, 0.f};

#pragma unroll 4
  for (int p = 0; p < 16; p++) {  // stream ref tiles
    bf16x8 af = Al[p * 64 + lane];
#pragma unroll
    for (int q = 0; q < 4; q++) {
      f32x16 d = __builtin_amdgcn_mfma_f32_32x32x16_bf16(af, bfr[q], zacc, 0, 0, 0);
      // 16 regs = 16 ref rows for this lane's query col -> 8 chained v_min3
      acc[q] = fminf(fminf(d[0], d[1]), acc[q]);
      acc[q] = fminf(fminf(d[2], d[3]), acc[q]);
      acc[q] = fminf(fminf(d[4], d[5]), acc[q]);
      acc[q] = fminf(fminf(d[6], d[7]), acc[q]);
      acc[q] = fminf(fminf(d[8], d[9]), acc[q]);
      acc[q] = fminf(fminf(d[10], d[11]), acc[q]);
      acc[q] = fminf(fminf(d[12], d[13]), acc[q]);
      acc[q] = fminf(fminf(d[14], d[15]), acc[q]);
    }
  }

  // epilogue: combine row halves, plain coalesced store of raw mins
  float* __restrict__ Pq = partial + ((size_t)(z * NJX + jx)) * NPTS + qbase;
#pragma unroll
  for (int q = 0; q < 4; q++) {
    float v = fminf(acc[q], __shfl_xor(acc[q], 32));
    if (lane < 32) Pq[(w * 4 + q) * 32 + n] = v;
  }
}

// 64 blocks: 8 per (dir,b) slice; fold NJX=16 jx partials per query (float4,
// coalesced), add qn, relu, mask, reduce, atomicAdd; LAST block (ticket)
// combines the 13 accumulators + l1part and writes out. 64 fences total: cheap.
__global__ __launch_bounds__(256) void reduce_kernel(
    const int* __restrict__ mask, const float* __restrict__ partial,
    const float* __restrict__ qnClean, const float* __restrict__ qnPred,
    const float* __restrict__ l1part, Accum* __restrict__ acc,
    float* __restrict__ out) {
  int slice = blockIdx.x >> 3, sub = blockIdx.x & 7;
  int dir = slice >> 2, bb = slice & 3;
  int t = threadIdx.x;
  const float4* __restrict__ qn4 =
      (const float4*)((dir ? qnPred : qnClean) + bb * NPTS + sub * 1024);
  const int4* __restrict__ mk4 = (const int4*)(mask + bb * NPTS + sub * 1024);
  const float* __restrict__ P = partial + (size_t)slice * NJX * NPTS + sub * 1024;

  // thread t owns queries [4t..4t+3]
  float4 v = ((const float4*)P)[t];
#pragma unroll
  for (int j = 1; j < NJX; j++) {
    float4 u = *(const float4*)(P + (size_t)j * NPTS + 4 * t);
    v.x = fminf(v.x, u.x); v.y = fminf(v.y, u.y);
    v.z = fminf(v.z, u.z); v.w = fminf(v.w, u.w);
  }
  float4 qv = qn4[t];
  int4 mm = mk4[t];
  float s = mm.x * fmaxf(v.x + qv.x, 0.f) + mm.y * fmaxf(v.y + qv.y, 0.f) +
            mm.z * fmaxf(v.z + qv.z, 0.f) + mm.w * fmaxf(v.w + qv.w, 0.f);
  float c = (float)(mm.x + mm.y + mm.z + mm.w);
  for (int off = 32; off; off >>= 1) {
    s += __shfl_down(s, off);
    c += __shfl_down(c, off);
  }
  __shared__ float rs[4], rc[4];
  int wave = t >> 6;
  if ((t & 63) == 0) { rs[wave] = s; rc[wave] = c; }
  __syncthreads();
  if (t == 0) {
    atomicAdd(&acc->minsum[slice], rs[0] + rs[1] + rs[2] + rs[3]);
    if (dir == 0) atomicAdd(&acc->count[bb], rc[0] + rc[1] + rc[2] + rc[3]);
  }

  // ---- ticket: last of 64 blocks computes the final scalar ----
  __threadfence();
  __shared__ unsigned int tk;
  if (t == 0) tk = atomicAdd(&acc->ticket, 1u);
  __syncthreads();
  if (tk != 63u) return;

  float l1 = (t < 128) ? l1part[t] : 0.f;
  for (int off = 32; off; off >>= 1) l1 += __shfl_down(l1, off);
  if ((t & 63) == 0) rs[t >> 6] = l1;
  __syncthreads();
  if (t == 0) {
    float l1s = rs[0] + rs[1];
    // device-coherent reads of the accumulators (atomic RMW with 0)
    float msum = 0.f, cham = 0.f;
#pragma unroll
    for (int b = 0; b < BATCH; b++) {
      float cnt = atomicAdd(&acc->count[b], 0.f);
      float m0 = atomicAdd(&acc->minsum[b], 0.f);
      float m1 = atomicAdd(&acc->minsum[4 + b], 0.f);
      msum += cnt;
      cham += (m0 + m1) / fmaxf(cnt, 1.f);
    }
    out[0] = 0.5f * (l1s / msum + cham * (1.f / BATCH));
  }
}

extern "C" void kernel_launch(void* const* d_in, const int* in_sizes, int n_in,
                              void* d_out, int out_size, void* d_ws, size_t ws_size,
                              hipStream_t stream) {
  const float* pred   = (const float*)d_in[0];
  const float* target = (const float*)d_in[1];
  const int*   mask   = (const int*)d_in[2];
  const float* points = (const float*)d_in[3];
  float* out = (float*)d_out;

  const int NP = BATCH * NPTS;  // 32768
  uint4* Apred  = (uint4*)d_ws;            // 1 MB each
  uint4* Aclean = Apred + NP * 2;
  uint4* Bclean = Aclean + NP * 2;
  uint4* Bpred  = Bclean + NP * 2;
  float* qnClean = (float*)(Bpred + NP * 2);   // 128 KB each
  float* qnPred  = qnClean + NP;
  float* partial = qnPred + NP;                // 8*NJX*NPTS floats = 4 MB
  float* l1part  = partial + 8 * NJX * NPTS;   // 128 floats
  Accum* acc     = (Accum*)(l1part + 128);

  prep_kernel<<<NP / 256, 256, 0, stream>>>(
      pred, target, mask, points, Apred, Aclean, Bclean, Bpred,
      qnClean, qnPred, l1part, acc);

  dim3 grid(NJX, NPTS / CHUNK, 2 * BATCH);  // (16,16,8) = 2048 blocks
  chamfer_kernel<<<grid, 256, 0, stream>>>(
      Apred, Aclean, Bclean, Bpred, partial);

  reduce_kernel<<<64, 256, 0, stream>>>(
      mask, partial, qnClean, qnPred, l1part, acc, out);
}

// Round 8
// 95.648 us; speedup vs baseline: 1.0358x; 1.0358x over previous
//
#include <hip/hip_runtime.h>
#include <stdint.h>

#define NPTS 8192
#define BATCH 4
#define CHUNK 512           // refs per block == queries per block
#define NJX (NPTS / CHUNK)  // 16 jx slices

typedef __attribute__((ext_vector_type(8))) short bf16x8;   // 8 bf16 = 4 VGPRs
typedef __attribute__((ext_vector_type(16))) float f32x16;  // 32x32 MFMA acc

// Accum: 13 floats + ticket, zeroed by chamfer block (0,0,0) via atomicExch
// (reduce is graph-ordered after all chamfer blocks -> init is always visible).
struct Accum {
  float l1sum;          // [0]
  float count[BATCH];   // [1..4]
  float minsum[8];      // [5..12]  [dir*4+b]
  unsigned int ticket;  // [13]
  unsigned int pad[2];
};

__device__ __forceinline__ unsigned short f2bf(float x) {  // RNE fp32->bf16
  union { float f; unsigned u; } v; v.f = x;
  unsigned r = v.u + 0x7FFFu + ((v.u >> 16) & 1u);
  return (unsigned short)(r >> 16);
}
__device__ __forceinline__ float bf2f(unsigned short h) {
  union { float f; unsigned u; } v; v.u = ((unsigned)h) << 16;
  return v.f;
}

// Fragment-order pack: per 32-point tile T, 64 uint4 chunks; chunk T*64 + lane
// = K-slots [8*(lane>>5)..] of point T*32+(lane&31). Fragment loads are
// lane-consecutive 16 B -> conflict-free b128.
// A (ref):   k0-3=[-2x_h,-2x_h,-2x_l,-2x_l] k4-7=y k8-11=z k12-14=3-split(norm+pen) k15=0
// B (query): k0-3=[x_h,x_l,x_h,x_l]         k4-7=y k8-11=z k12-14=[1,1,1]          k15=0
// => D[ref m][query n] = (norm_r + pen) - 2 q.r  (exact hi/lo product pairing;
// query norm + relu applied in reduce -- both commute with min over refs).
__device__ __forceinline__ void writeA_lds(uint4* P, int T, int n,
                                           float x, float y, float z, float nn) {
  float ax = -2.f * x, ay = -2.f * y, az = -2.f * z;
  unsigned xh = f2bf(ax), xl = f2bf(ax - bf2f(xh));
  unsigned yh = f2bf(ay), yl = f2bf(ay - bf2f(yh));
  unsigned zh = f2bf(az), zl = f2bf(az - bf2f(zh));
  unsigned nh = f2bf(nn);
  float rem = nn - bf2f((unsigned short)nh);
  unsigned nm = f2bf(rem);
  unsigned nl = f2bf(rem - bf2f((unsigned short)nm));
  uint4 h0, h1;
  h0.x = xh | (xh << 16); h0.y = xl | (xl << 16);
  h0.z = yh | (yh << 16); h0.w = yl | (yl << 16);
  h1.x = zh | (zh << 16); h1.y = zl | (zl << 16);
  h1.z = nh | (nm << 16); h1.w = nl;
  P[T * 64 + n] = h0;
  P[T * 64 + 32 + n] = h1;
}

// 2048 blocks = (jx, qy, dir*4+b). Fully fused: packs its own refs (LDS) and
// query fragments (registers), runs the verified MFMA/min3 core, stores raw
// row-mins to a PRIVATE partial slice. No atomics/fences in the hot path.
__global__ __launch_bounds__(256) void chamfer_kernel(
    const float* __restrict__ pred, const float* __restrict__ target,
    const int* __restrict__ mask, const float* __restrict__ points,
    float* __restrict__ partial, Accum* __restrict__ accg) {
  __shared__ uint4 Asm[1024];  // 16 KB: 16 ref tiles, fragment order
  int z = blockIdx.z, dir = z >> 2, b = z & 3;
  // dir0: refs = pred-denoised, queries = clean ; dir1: swapped
  const float* __restrict__ dr = dir ? target : pred;
  const float* __restrict__ dq = dir ? pred : target;
  int jbase = blockIdx.x * CHUNK;
  int qbase = blockIdx.y * CHUNK;
  int tid = threadIdx.x;

  if (blockIdx.x == 0 && blockIdx.y == 0 && z == 0 && tid < 16)
    atomicExch((unsigned int*)accg + tid, 0u);  // init accumulators + ticket

  // ---- pack 512 refs -> LDS (2 points per thread) ----
  for (int i = tid; i < CHUNK; i += 256) {
    int g = b * NPTS + jbase + i;
    float rx = points[3 * g] + dr[3 * g];
    float ry = points[3 * g + 1] + dr[3 * g + 1];
    float rz = points[3 * g + 2] + dr[3 * g + 2];
    float rn = rx * rx + ry * ry + rz * rz + (mask[g] ? 0.f : 1e9f);
    writeA_lds(Asm, i >> 5, i & 31, rx, ry, rz, rn);
  }

  // ---- direct-pack this lane's 4 query fragments in registers ----
  int lane = tid & 63, w = tid >> 6, n = lane & 31, h = lane >> 5;
  const unsigned ONE = 0x3F80u;
  union Frag { bf16x8 v; unsigned u[4]; };
  Frag bfr[4];
  float acc[4];
#pragma unroll
  for (int q = 0; q < 4; q++) {
    int g = b * NPTS + qbase + (w * 4 + q) * 32 + n;
    float qx = points[3 * g] + dq[3 * g];
    float qy = points[3 * g + 1] + dq[3 * g + 1];
    float qz = points[3 * g + 2] + dq[3 * g + 2];
    if (h == 0) {
      unsigned xh = f2bf(qx), xl = f2bf(qx - bf2f((unsigned short)xh));
      unsigned yh = f2bf(qy), yl = f2bf(qy - bf2f((unsigned short)yh));
      unsigned ux = xh | (xl << 16), uy = yh | (yl << 16);
      bfr[q].u[0] = ux; bfr[q].u[1] = ux; bfr[q].u[2] = uy; bfr[q].u[3] = uy;
    } else {
      unsigned zh = f2bf(qz), zl = f2bf(qz - bf2f((unsigned short)zh));
      unsigned uz = zh | (zl << 16);
      bfr[q].u[0] = uz; bfr[q].u[1] = uz;
      bfr[q].u[2] = ONE | (ONE << 16); bfr[q].u[3] = ONE;
    }
    acc[q] = 1e30f;
  }
  __syncthreads();  // ref pack visible to all waves

  const bf16x8* Al = (const bf16x8*)Asm;
  f32x16 zacc = {0.f, 0.f, 0.f, 0.f, 0.f, 0.f, 0.f, 0.f,
                 0.f, 0.f, 0.f, 0.f, 0.f, 0.f, 0.f, 0.f};

#pragma unroll 4
  for (int p = 0; p < 16; p++) {  // stream ref tiles
    bf16x8 af = Al[p * 64 + lane];
#pragma unroll
    for (int q = 0; q < 4; q++) {
      f32x16 d = __builtin_amdgcn_mfma_f32_32x32x16_bf16(af, bfr[q].v, zacc, 0, 0, 0);
      // 16 regs = 16 ref rows for this lane's query col -> 8 chained v_min3
      acc[q] = fminf(fminf(d[0], d[1]), acc[q]);
      acc[q] = fminf(fminf(d[2], d[3]), acc[q]);
      acc[q] = fminf(fminf(d[4], d[5]), acc[q]);
      acc[q] = fminf(fminf(d[6], d[7]), acc[q]);
      acc[q] = fminf(fminf(d[8], d[9]), acc[q]);
      acc[q] = fminf(fminf(d[10], d[11]), acc[q]);
      acc[q] = fminf(fminf(d[12], d[13]), acc[q]);
      acc[q] = fminf(fminf(d[14], d[15]), acc[q]);
    }
  }

  // epilogue: combine row halves, plain coalesced store of raw mins
  float* __restrict__ Pq = partial + ((size_t)(z * NJX + blockIdx.x)) * NPTS + qbase;
#pragma unroll
  for (int q = 0; q < 4; q++) {
    float v = fminf(acc[q], __shfl_xor(acc[q], 32));
    if (lane < 32) Pq[(w * 4 + q) * 32 + n] = v;
  }
}

// 64 blocks: 8 per (dir,b) slice. Fold 16 jx partials per query, recompute qn
// from raw inputs, relu, mask; dir0 blocks also do count + L1. atomicAdd once
// per block; ticket-last block (64 fences total) writes the final scalar.
__global__ __launch_bounds__(256) void reduce_kernel(
    const float* __restrict__ pred, const float* __restrict__ target,
    const int* __restrict__ mask, const float* __restrict__ points,
    const float* __restrict__ partial, Accum* __restrict__ acc,
    float* __restrict__ out) {
  int slice = blockIdx.x >> 3, sub = blockIdx.x & 7;
  int dir = slice >> 2, bb = slice & 3;
  const float* __restrict__ dq = dir ? pred : target;  // query coords source
  int t = threadIdx.x;
  int base = bb * NPTS + sub * 1024;
  const float* __restrict__ P = partial + (size_t)slice * NJX * NPTS + sub * 1024;

  // thread t owns queries [4t .. 4t+3]
  float4 v = ((const float4*)P)[t];
#pragma unroll
  for (int j = 1; j < NJX; j++) {
    float4 u = *(const float4*)(P + (size_t)j * NPTS + 4 * t);
    v.x = fminf(v.x, u.x); v.y = fminf(v.y, u.y);
    v.z = fminf(v.z, u.z); v.w = fminf(v.w, u.w);
  }
  float vv[4] = {v.x, v.y, v.z, v.w};
  float s = 0.f, c = 0.f, l1 = 0.f;
#pragma unroll
  for (int k = 0; k < 4; k++) {
    int g = base + 4 * t + k;
    float qx = points[3 * g] + dq[3 * g];
    float qy = points[3 * g + 1] + dq[3 * g + 1];
    float qz = points[3 * g + 2] + dq[3 * g + 2];
    float qn = qx * qx + qy * qy + qz * qz;
    float m = (float)mask[g];
    s += m * fmaxf(vv[k] + qn, 0.f);
    c += m;
    if (dir == 0)
      l1 += m * (fabsf(pred[3 * g] - target[3 * g]) +
                 fabsf(pred[3 * g + 1] - target[3 * g + 1]) +
                 fabsf(pred[3 * g + 2] - target[3 * g + 2])) * (1.f / 3.f);
  }
  for (int off = 32; off; off >>= 1) {
    s += __shfl_down(s, off);
    c += __shfl_down(c, off);
    l1 += __shfl_down(l1, off);
  }
  __shared__ float rs[4], rc[4], rl[4];
  int wave = t >> 6;
  if ((t & 63) == 0) { rs[wave] = s; rc[wave] = c; rl[wave] = l1; }
  __syncthreads();
  if (t == 0) {
    atomicAdd(&acc->minsum[slice], rs[0] + rs[1] + rs[2] + rs[3]);
    if (dir == 0) {
      atomicAdd(&acc->count[bb], rc[0] + rc[1] + rc[2] + rc[3]);
      atomicAdd(&acc->l1sum, rl[0] + rl[1] + rl[2] + rl[3]);
    }
  }

  // ---- ticket: last of 64 blocks computes the final scalar ----
  __threadfence();
  __shared__ unsigned int tk;
  if (t == 0) tk = atomicAdd(&acc->ticket, 1u);
  __syncthreads();
  if (tk != 63u) return;
  if (t == 0) {
    float l1s = atomicAdd(&acc->l1sum, 0.f);  // device-coherent reads
    float msum = 0.f, cham = 0.f;
#pragma unroll
    for (int b = 0; b < BATCH; b++) {
      float cnt = atomicAdd(&acc->count[b], 0.f);
      float m0 = atomicAdd(&acc->minsum[b], 0.f);
      float m1 = atomicAdd(&acc->minsum[4 + b], 0.f);
      msum += cnt;
      cham += (m0 + m1) / fmaxf(cnt, 1.f);
    }
    out[0] = 0.5f * (l1s / msum + cham * (1.f / BATCH));
  }
}

extern "C" void kernel_launch(void* const* d_in, const int* in_sizes, int n_in,
                              void* d_out, int out_size, void* d_ws, size_t ws_size,
                              hipStream_t stream) {
  const float* pred   = (const float*)d_in[0];
  const float* target = (const float*)d_in[1];
  const int*   mask   = (const int*)d_in[2];
  const float* points = (const float*)d_in[3];
  float* out = (float*)d_out;

  float* partial = (float*)d_ws;               // 8*NJX*NPTS floats = 4 MB
  Accum* acc = (Accum*)(partial + 8 * NJX * NPTS);

  dim3 grid(NJX, NPTS / CHUNK, 2 * BATCH);  // (16,16,8) = 2048 blocks
  chamfer_kernel<<<grid, 256, 0, stream>>>(pred, target, mask, points, partial, acc);

  reduce_kernel<<<64, 256, 0, stream>>>(pred, target, mask, points, partial, acc, out);
}